// Round 1
// baseline (638.295 us; speedup 1.0000x reference)
//
#include <hip/hip_runtime.h>

#define BATCH   16384
#define KK      26
#define VDIM    128
#define NWORDS  100000

// ---------------------------------------------------------------------------
// Kernel 1: transpose O [VDIM, NWORDS] -> Ot [NWORDS, VDIM]
// Tile: 128 (v) x 32 (w). Both global read and write coalesced via LDS.
// ---------------------------------------------------------------------------
__global__ __launch_bounds__(256) void transpose_O(const float* __restrict__ O,
                                                   float* __restrict__ Ot) {
    __shared__ float tile[VDIM * 33];  // [v][w], leading dim 33 to break conflicts
    const int wbase = blockIdx.x * 32;
    const int t = threadIdx.x;

    // Read phase: 128*32 = 4096 elements, 256 threads x 16 iters.
    // idx = v*32 + w  -> consecutive lanes read consecutive w (contiguous 128B rows)
    #pragma unroll
    for (int i = 0; i < 16; ++i) {
        int idx = i * 256 + t;
        int v = idx >> 5;        // /32
        int w = idx & 31;
        tile[v * 33 + w] = O[(size_t)v * NWORDS + (wbase + w)];
    }
    __syncthreads();

    // Write phase: idx = w*128 + v -> consecutive lanes write consecutive v
    // (contiguous 512B per word row of Ot)
    #pragma unroll
    for (int i = 0; i < 16; ++i) {
        int idx = i * 256 + t;
        int w = idx >> 7;        // /128
        int v = idx & 127;
        Ot[(size_t)(wbase + w) * VDIM + v] = tile[v * 33 + w];
    }
}

// ---------------------------------------------------------------------------
// Kernel 2: gather-dot using transposed Ot (rows contiguous, 512B each).
// One block per batch element; 4 waves; each wave handles k = wave, wave+4, ...
// Lane l covers v = 2l, 2l+1 (float2), then 64-lane shuffle reduction.
// ---------------------------------------------------------------------------
__global__ __launch_bounds__(256) void gather_dot(const int* __restrict__ doc_ids,
                                                  const int* __restrict__ tn_ids,
                                                  const float* __restrict__ D,
                                                  const float* __restrict__ Ot,
                                                  float* __restrict__ out) {
    __shared__ float d_s[VDIM];
    const int b = blockIdx.x;

    if (threadIdx.x < VDIM) {
        const int doc = doc_ids[b];
        d_s[threadIdx.x] = D[(size_t)doc * VDIM + threadIdx.x];
    }
    __syncthreads();

    const int wave = threadIdx.x >> 6;
    const int lane = threadIdx.x & 63;
    const float2 dv = *(const float2*)&d_s[lane * 2];

    for (int k = wave; k < KK; k += 4) {
        const int word = tn_ids[b * KK + k];
        const float2 wv = *(const float2*)&Ot[(size_t)word * VDIM + lane * 2];
        float p = dv.x * wv.x + dv.y * wv.y;
        #pragma unroll
        for (int off = 32; off > 0; off >>= 1)
            p += __shfl_down(p, off);
        if (lane == 0) out[b * KK + k] = p;
    }
}

// ---------------------------------------------------------------------------
// Fallback (only if ws_size < 51.2 MB): direct strided column gather of O.
// Correct but slow; not expected to be used.
// ---------------------------------------------------------------------------
__global__ __launch_bounds__(256) void gather_dot_direct(const int* __restrict__ doc_ids,
                                                         const int* __restrict__ tn_ids,
                                                         const float* __restrict__ D,
                                                         const float* __restrict__ O,
                                                         float* __restrict__ out) {
    __shared__ float d_s[VDIM];
    const int b = blockIdx.x;

    if (threadIdx.x < VDIM) {
        const int doc = doc_ids[b];
        d_s[threadIdx.x] = D[(size_t)doc * VDIM + threadIdx.x];
    }
    __syncthreads();

    const int wave = threadIdx.x >> 6;
    const int lane = threadIdx.x & 63;
    const int v0 = lane * 2;
    const float2 dv = *(const float2*)&d_s[v0];

    for (int k = wave; k < KK; k += 4) {
        const int word = tn_ids[b * KK + k];
        float p = dv.x * O[(size_t)v0 * NWORDS + word]
                + dv.y * O[(size_t)(v0 + 1) * NWORDS + word];
        #pragma unroll
        for (int off = 32; off > 0; off >>= 1)
            p += __shfl_down(p, off);
        if (lane == 0) out[b * KK + k] = p;
    }
}

extern "C" void kernel_launch(void* const* d_in, const int* in_sizes, int n_in,
                              void* d_out, int out_size, void* d_ws, size_t ws_size,
                              hipStream_t stream) {
    // setup_inputs order: context_ids, doc_ids, target_noise_ids, D, O
    const int*   doc_ids = (const int*)d_in[1];
    const int*   tn_ids  = (const int*)d_in[2];
    const float* D       = (const float*)d_in[3];
    const float* O       = (const float*)d_in[4];
    float*       out     = (float*)d_out;

    const size_t ot_bytes = (size_t)NWORDS * VDIM * sizeof(float);

    if (ws_size >= ot_bytes) {
        float* Ot = (float*)d_ws;
        transpose_O<<<NWORDS / 32, 256, 0, stream>>>(O, Ot);
        gather_dot<<<BATCH, 256, 0, stream>>>(doc_ids, tn_ids, D, Ot, out);
    } else {
        gather_dot_direct<<<BATCH, 256, 0, stream>>>(doc_ids, tn_ids, D, O, out);
    }
}

// Round 2
// 620.422 us; speedup vs baseline: 1.0288x; 1.0288x over previous
//
#include <hip/hip_runtime.h>

#define BATCH   16384
#define KK      26
#define VDIM    128
#define NWORDS  100000

// ---------------------------------------------------------------------------
// Kernel 1: transpose O [VDIM, NWORDS] -> Ot [NWORDS, VDIM]
// Tile: 128 (v) x 32 (w). float4 on both global phases.
// ---------------------------------------------------------------------------
__global__ __launch_bounds__(256) void transpose_O(const float* __restrict__ O,
                                                   float* __restrict__ Ot) {
    __shared__ float tile[VDIM][33];  // +1 pad breaks bank conflicts
    const int wbase = blockIdx.x * 32;
    const int t = threadIdx.x;

    // Read: 4096 elems = 1024 float4, 4 iters. Lane-consecutive w -> coalesced.
    #pragma unroll
    for (int i = 0; i < 4; ++i) {
        int idx = i * 256 + t;          // 0..1023
        int v = idx >> 3;               // 0..127
        int w = (idx & 7) * 4;          // 0,4,..,28
        float4 r = *(const float4*)&O[(size_t)v * NWORDS + wbase + w];
        tile[v][w] = r.x; tile[v][w + 1] = r.y;
        tile[v][w + 2] = r.z; tile[v][w + 3] = r.w;
    }
    __syncthreads();

    // Write: lane-consecutive v -> contiguous 512B rows of Ot, float4 stores.
    #pragma unroll
    for (int i = 0; i < 4; ++i) {
        int idx = i * 256 + t;
        int w = idx >> 5;               // 0..31
        int v = (idx & 31) * 4;         // 0,4,..,124
        float4 r = make_float4(tile[v][w], tile[v + 1][w],
                               tile[v + 2][w], tile[v + 3][w]);
        *(float4*)&Ot[(size_t)(wbase + w) * VDIM + v] = r;
    }
}

// ---------------------------------------------------------------------------
// Kernel 2: gather-dot. One block per b; 8 groups of 32 lanes; each group
// handles k = g, g+8, g+16, g+24. Lane l covers v = 4l..4l+3 (float4, 32
// lanes = one full 512B Ot row). Width-32 shuffle reduction (5 steps).
// ---------------------------------------------------------------------------
__global__ __launch_bounds__(256) void gather_dot(const int* __restrict__ doc_ids,
                                                  const int* __restrict__ tn_ids,
                                                  const float* __restrict__ D,
                                                  const float* __restrict__ Ot,
                                                  float* __restrict__ out) {
    __shared__ float d_s[VDIM];
    const int b = blockIdx.x;

    if (threadIdx.x < VDIM) {
        const int doc = doc_ids[b];
        d_s[threadIdx.x] = D[(size_t)doc * VDIM + threadIdx.x];
    }
    __syncthreads();

    const int g = threadIdx.x >> 5;     // 0..7
    const int l = threadIdx.x & 31;
    const float4 dv = *(const float4*)&d_s[l * 4];

    for (int k = g; k < KK; k += 8) {
        const int word = tn_ids[b * KK + k];
        const float4 wv = *(const float4*)&Ot[(size_t)word * VDIM + l * 4];
        float p = dv.x * wv.x + dv.y * wv.y + dv.z * wv.z + dv.w * wv.w;
        #pragma unroll
        for (int off = 16; off > 0; off >>= 1)
            p += __shfl_down(p, off, 32);
        if (l == 0) out[b * KK + k] = p;
    }
}

// ---------------------------------------------------------------------------
// Fallback (only if ws_size < 51.2 MB): direct strided column gather of O.
// ---------------------------------------------------------------------------
__global__ __launch_bounds__(256) void gather_dot_direct(const int* __restrict__ doc_ids,
                                                         const int* __restrict__ tn_ids,
                                                         const float* __restrict__ D,
                                                         const float* __restrict__ O,
                                                         float* __restrict__ out) {
    __shared__ float d_s[VDIM];
    const int b = blockIdx.x;

    if (threadIdx.x < VDIM) {
        const int doc = doc_ids[b];
        d_s[threadIdx.x] = D[(size_t)doc * VDIM + threadIdx.x];
    }
    __syncthreads();

    const int wave = threadIdx.x >> 6;
    const int lane = threadIdx.x & 63;
    const int v0 = lane * 2;
    const float2 dv = *(const float2*)&d_s[v0];

    for (int k = wave; k < KK; k += 4) {
        const int word = tn_ids[b * KK + k];
        float p = dv.x * O[(size_t)v0 * NWORDS + word]
                + dv.y * O[(size_t)(v0 + 1) * NWORDS + word];
        #pragma unroll
        for (int off = 32; off > 0; off >>= 1)
            p += __shfl_down(p, off);
        if (lane == 0) out[b * KK + k] = p;
    }
}

extern "C" void kernel_launch(void* const* d_in, const int* in_sizes, int n_in,
                              void* d_out, int out_size, void* d_ws, size_t ws_size,
                              hipStream_t stream) {
    // setup_inputs order: context_ids, doc_ids, target_noise_ids, D, O
    const int*   doc_ids = (const int*)d_in[1];
    const int*   tn_ids  = (const int*)d_in[2];
    const float* D       = (const float*)d_in[3];
    const float* O       = (const float*)d_in[4];
    float*       out     = (float*)d_out;

    const size_t ot_bytes = (size_t)NWORDS * VDIM * sizeof(float);

    if (ws_size >= ot_bytes) {
        float* Ot = (float*)d_ws;
        transpose_O<<<NWORDS / 32, 256, 0, stream>>>(O, Ot);
        gather_dot<<<BATCH, 256, 0, stream>>>(doc_ids, tn_ids, D, Ot, out);
    } else {
        gather_dot_direct<<<BATCH, 256, 0, stream>>>(doc_ids, tn_ids, D, O, out);
    }
}

// Round 3
// 615.846 us; speedup vs baseline: 1.0365x; 1.0074x over previous
//
#include <hip/hip_runtime.h>

#define BATCH   16384
#define KK      26
#define VDIM    128
#define NWORDS  100000

// DPP-shifted copy of x (0-fill out of row), added by caller. VALU-speed
// cross-lane: row_shr:n = 0x110|n, row_bcast15 = 0x142.
template <int CTRL>
__device__ __forceinline__ float dpp_mov(float x) {
    int xi = __builtin_bit_cast(int, x);
    int yi = __builtin_amdgcn_update_dpp(0, xi, CTRL, 0xF, 0xF, true);
    return __builtin_bit_cast(float, yi);
}

// ---------------------------------------------------------------------------
// Kernel 1: transpose O [VDIM, NWORDS] -> Ot [NWORDS, VDIM]
// Read float4 rows of O, scatter into tile[w][v] (pad 129 -> ~2-way conflicts,
// free on wave64); write phase is ds_read_b128 + coalesced float4 stores.
// ---------------------------------------------------------------------------
__global__ __launch_bounds__(256) void transpose_O(const float* __restrict__ O,
                                                   float* __restrict__ Ot) {
    __shared__ float tile[32][129];  // [w][v], pad breaks conflicts
    const int wbase = blockIdx.x * 32;
    const int t = threadIdx.x;

    #pragma unroll
    for (int i = 0; i < 4; ++i) {
        int idx = i * 256 + t;          // 0..1023
        int v = idx >> 3;               // 0..127
        int w4 = (idx & 7) * 4;         // 0,4,..,28
        float4 r = *(const float4*)&O[(size_t)v * NWORDS + wbase + w4];
        tile[w4 + 0][v] = r.x;
        tile[w4 + 1][v] = r.y;
        tile[w4 + 2][v] = r.z;
        tile[w4 + 3][v] = r.w;
    }
    __syncthreads();

    #pragma unroll
    for (int i = 0; i < 4; ++i) {
        int idx = i * 256 + t;
        int w = idx >> 5;               // 0..31
        int v = (idx & 31) * 4;         // 0,4,..,124
        *(float4*)&Ot[(size_t)(wbase + w) * VDIM + v] =
            *(const float4*)&tile[w][v];
    }
}

// ---------------------------------------------------------------------------
// Kernel 2: gather-dot. One block per b; 8 groups of 32 lanes; group g
// handles k = g, g+8, g+16, g+24. No LDS, no syncthreads. All word-ids then
// all 4 Ot row loads issued up front (4x memory-level parallelism), then
// DPP-based 32-lane reductions (pure VALU, no ds_bpermute).
// ---------------------------------------------------------------------------
__global__ __launch_bounds__(256) void gather_dot(const int* __restrict__ doc_ids,
                                                  const int* __restrict__ tn_ids,
                                                  const float* __restrict__ D,
                                                  const float* __restrict__ Ot,
                                                  float* __restrict__ out) {
    const int b = blockIdx.x;
    const int t = threadIdx.x;
    const int g = t >> 5;               // 0..7
    const int l = t & 31;

    const int doc = doc_ids[b];         // uniform -> scalar load
    const float4 dv = *(const float4*)&D[(size_t)doc * VDIM + l * 4];

    const int base = b * KK;
    int word[4];
    #pragma unroll
    for (int j = 0; j < 4; ++j) {
        int k = g + 8 * j;
        word[j] = (k < KK) ? tn_ids[base + k] : -1;
    }

    float4 wv[4];
    #pragma unroll
    for (int j = 0; j < 4; ++j) {
        if (word[j] >= 0)
            wv[j] = *(const float4*)&Ot[(size_t)word[j] * VDIM + l * 4];
    }

    #pragma unroll
    for (int j = 0; j < 4; ++j) {
        int k = g + 8 * j;
        if (k < KK) {
            float p = dv.x * wv[j].x + dv.y * wv[j].y
                    + dv.z * wv[j].z + dv.w * wv[j].w;
            p += dpp_mov<0x111>(p);     // row_shr:1
            p += dpp_mov<0x112>(p);     // row_shr:2
            p += dpp_mov<0x114>(p);     // row_shr:4
            p += dpp_mov<0x118>(p);     // row_shr:8  -> lane15/31/47/63 hold row sums
            p += dpp_mov<0x142>(p);     // row_bcast15 -> lane31/63 hold 32-lane sums
            if (l == 31) out[base + k] = p;
        }
    }
}

// ---------------------------------------------------------------------------
// Fallback (only if ws_size < 51.2 MB): direct strided column gather of O.
// ---------------------------------------------------------------------------
__global__ __launch_bounds__(256) void gather_dot_direct(const int* __restrict__ doc_ids,
                                                         const int* __restrict__ tn_ids,
                                                         const float* __restrict__ D,
                                                         const float* __restrict__ O,
                                                         float* __restrict__ out) {
    __shared__ float d_s[VDIM];
    const int b = blockIdx.x;

    if (threadIdx.x < VDIM) {
        const int doc = doc_ids[b];
        d_s[threadIdx.x] = D[(size_t)doc * VDIM + threadIdx.x];
    }
    __syncthreads();

    const int wave = threadIdx.x >> 6;
    const int lane = threadIdx.x & 63;
    const int v0 = lane * 2;
    const float2 dv = *(const float2*)&d_s[v0];

    for (int k = wave; k < KK; k += 4) {
        const int word = tn_ids[b * KK + k];
        float p = dv.x * O[(size_t)v0 * NWORDS + word]
                + dv.y * O[(size_t)(v0 + 1) * NWORDS + word];
        #pragma unroll
        for (int off = 32; off > 0; off >>= 1)
            p += __shfl_down(p, off);
        if (lane == 0) out[b * KK + k] = p;
    }
}

extern "C" void kernel_launch(void* const* d_in, const int* in_sizes, int n_in,
                              void* d_out, int out_size, void* d_ws, size_t ws_size,
                              hipStream_t stream) {
    // setup_inputs order: context_ids, doc_ids, target_noise_ids, D, O
    const int*   doc_ids = (const int*)d_in[1];
    const int*   tn_ids  = (const int*)d_in[2];
    const float* D       = (const float*)d_in[3];
    const float* O       = (const float*)d_in[4];
    float*       out     = (float*)d_out;

    const size_t ot_bytes = (size_t)NWORDS * VDIM * sizeof(float);

    if (ws_size >= ot_bytes) {
        float* Ot = (float*)d_ws;
        transpose_O<<<NWORDS / 32, 256, 0, stream>>>(O, Ot);
        gather_dot<<<BATCH, 256, 0, stream>>>(doc_ids, tn_ids, D, Ot, out);
    } else {
        gather_dot_direct<<<BATCH, 256, 0, stream>>>(doc_ids, tn_ids, D, O, out);
    }
}